// Round 5
// baseline (130.210 us; speedup 1.0000x reference)
//
#include <hip/hip_runtime.h>

// B=128, K=256, M=8, D=128 ; rows = B*K = 32768 flattened (b,k)
#define LT      20.0f
#define LN2     0.69314718055994531f
#define C2EXP   28.853900817779268f   // LT/ln2 : e^(LT*x) = 2^(C2EXP*x)
#define CHUNKS  16                    // 16 chunks x 128 prototype-cols = 2048
#define NBLK    1024                  // main grid: 1024 blocks x 512 threads
#define PW_COPY 262144                // halves per Pw copy (512 KB / 2B)

typedef _Float16 half8 __attribute__((ext_vector_type(8)));
typedef float    f32x4 __attribute__((ext_vector_type(4)));

#if __has_builtin(__builtin_amdgcn_exp2f)
#define EXP2F(x) __builtin_amdgcn_exp2f(x)
#else
#define EXP2F(x) __expf(0.69314718055994531f * (x))
#endif

__device__ __forceinline__ float swz16(float x) {
    // xor lane^16 within 32-lane halves (BitMode: xor=16, and=0x1F)
    return __int_as_float(__builtin_amdgcn_ds_swizzle(__float_as_int(x), 0x401F));
}

// async global->LDS, 16B per lane; lds base must be wave-uniform
#define GLD16(gp, lp) __builtin_amdgcn_global_load_lds( \
    (const __attribute__((address_space(1))) void*)(gp), \
    (__attribute__((address_space(3))) void*)(lp), 16, 0, 0)

// ---- prep: f32 P -> f16 scaled by C2EXP, packed in fragment lane order,
// REPLICATED 8x so each XCD's L2 gets its own full copy (block g -> XCD g%8).
// Within a copy: half8 slot id = ch*2048 + colq*512 + cfrag*64 + lane
//   c = cfrag&3 (K-slice), h = cfrag>>2 (proto half), n = lane&15, q = lane>>4
//   col = colq*32 + (n>>2)*8 + (n&3) + 4*h ; gcol = ch*128+col ; d = c*32+q*8
__global__ __launch_bounds__(256)
void mpcl_prep(const float* __restrict__ P, _Float16* __restrict__ Pw,
               int* __restrict__ ws)
{
    if (blockIdx.x == 0 && threadIdx.x == 0) ws[0] = 0;   // zero gcnt
    int copy = blockIdx.x & 7;
    int id   = (blockIdx.x >> 3) * 256 + threadIdx.x;     // 0..32767
    int ch    = id >> 11;
    int colq  = (id >> 9) & 3;
    int cfrag = (id >> 6) & 7;
    int lane  = id & 63;
    int n = lane & 15, q = lane >> 4;
    int c = cfrag & 3, h = cfrag >> 2;
    int col  = colq * 32 + ((n >> 2) << 3) + (n & 3) + (h << 2);
    int gcol = (ch << 7) + col;
    const float* src = P + ((size_t)gcol << 7) + c * 32 + q * 8;
    float4 a = *(const float4*)src;
    float4 b = *(const float4*)(src + 4);
    half8 hv;   // pre-scaled: MFMA emits y = C2EXP * sim directly
    hv[0] = (_Float16)(C2EXP * a.x); hv[1] = (_Float16)(C2EXP * a.y);
    hv[2] = (_Float16)(C2EXP * a.z); hv[3] = (_Float16)(C2EXP * a.w);
    hv[4] = (_Float16)(C2EXP * b.x); hv[5] = (_Float16)(C2EXP * b.y);
    hv[6] = (_Float16)(C2EXP * b.z); hv[7] = (_Float16)(C2EXP * b.w);
    *(half8*)(Pw + (size_t)copy * PW_COPY + (size_t)id * 8) = hv;
}

// Grid: 1024 blocks x 512 thr (8 waves) = exactly 4 blocks/CU, one
// co-residency generation. Block owns 32 rows x all 2048 cols.
// wave w: colq=w&3 (4 concepts/chunk), rh=(w>>2)&1 (16-row half).
// OCCUPANCY DESIGN (round-4 diagnosis: issue/stall-bound, 58% bubbles at
// 3-4 waves/SIMD): VGPR<=64 (launch_bounds 512,8) + single-buffer 32KB LDS
// => 32 waves/CU = 8 waves/SIMD. Stage latency is exposed per block, but
// 4 independent blocks/CU interleave to fill it (TLP instead of dbuf).
__global__ __launch_bounds__(512, 8)
void mpcl_main(const float* __restrict__ V,        // (32768, 128) f32
               const int*   __restrict__ labels,   // (32768)
               const _Float16* __restrict__ Pw,    // packed P, 8 copies
               int* __restrict__ ws,               // [0]=gcnt ; +256B: partials
               float* __restrict__ out)
{
    __shared__ __align__(16) _Float16 Pst[2048 * 8];   // 32 KB, single buffer
    __shared__ float sh_denom[32];
    __shared__ float sh_simpos[32];
    __shared__ float sh_fin[16];
    __shared__ int   sh_last;

    int*   gcnt = ws;
    float* part = (float*)((char*)ws + 256);

    const int tid  = threadIdx.x;
    const int lane = tid & 63;
    const int w    = tid >> 6;        // 0..7
    const int colq = w & 3;
    const int rh   = (w >> 2) & 1;    // 16-row half
    const int n    = lane & 15;
    const int q    = lane >> 4;
    const int rowbase = blockIdx.x * 32;

    if (tid < 32) { sh_denom[tid] = 0.0f; sh_simpos[tid] = 0.0f; }

    int lab = 0;
    if (tid < 32) lab = labels[rowbase + tid];    // prefetch early

    // XCD-local copy; wave w stages half8 slots [w*256, +256) of each chunk
    const _Float16* gbase = Pw + (size_t)(blockIdx.x & 7) * PW_COPY
                               + (size_t)(w * 256 + lane) * 8;

#define STAGE(CH) do {                                          \
    const _Float16* g_ = gbase + (size_t)(CH) * 16384;          \
    _Float16* l_ = &Pst[(w * 256) * 8];                         \
    GLD16(g_,        l_);                                       \
    GLD16(g_ +  512, l_ +  512);                                \
    GLD16(g_ + 1024, l_ + 1024);                                \
    GLD16(g_ + 1536, l_ + 1536);                                \
} while (0)

    // ---- V fragments (B operand): 16 rows, f16, register-resident (16 VGPR)
    half8 vh[4];
    {
        const float* vr = V + ((size_t)(rowbase + rh * 16 + n) << 7) + q * 8;
#pragma unroll
        for (int c = 0; c < 4; ++c) {
            float4 x0 = *(const float4*)(vr + c * 32);
            float4 x1 = *(const float4*)(vr + c * 32 + 4);
            vh[c][0] = (_Float16)x0.x; vh[c][1] = (_Float16)x0.y;
            vh[c][2] = (_Float16)x0.z; vh[c][3] = (_Float16)x0.w;
            vh[c][4] = (_Float16)x1.x; vh[c][5] = (_Float16)x1.y;
            vh[c][6] = (_Float16)x1.z; vh[c][7] = (_Float16)x1.w;
        }
    }

    const int rowk = (rowbase + rh * 16 + n) & 255;   // this row's own concept
    const int aoff = (colq * 512 + lane) * 8;         // half index of a1(c=0)

    float dn = 0.f;
    int cA = colq * 4 + q;

#pragma unroll 1
    for (int ch = 0; ch < CHUNKS; ++ch) {
        __syncthreads();                 // all waves done reading Pst (prev chunk)
        STAGE(ch);                       // 4 x GLD16 per wave
        asm volatile("s_waitcnt vmcnt(0)" ::: "memory");   // own DMA done
        __syncthreads();                 // everyone's DMA visible

        f32x4 acc1 = {0.f, 0.f, 0.f, 0.f};
        f32x4 acc2 = {0.f, 0.f, 0.f, 0.f};
#pragma unroll
        for (int c = 0; c < 4; ++c) {
            half8 a1 = *(const half8*)&Pst[aoff + c * 512];          // frag c
            half8 a2 = *(const half8*)&Pst[aoff + c * 512 + 2048];   // frag 4+c
            acc1 = __builtin_amdgcn_mfma_f32_16x16x32_f16(a1, vh[c], acc1, 0, 0, 0);
            acc2 = __builtin_amdgcn_mfma_f32_16x16x32_f16(a2, vh[c], acc2, 0, 0, 0);
        }

        // ---- epilogue: y = C2EXP*sim from MFMA; softmax-over-8 in-lane ----
        {
            float x0 = acc1[0], x1 = acc1[1], x2 = acc1[2], x3 = acc1[3];
            float x4 = acc2[0], x5 = acc2[1], x6 = acc2[2], x7 = acc2[3];
            float e0 = EXP2F(x0), e1 = EXP2F(x1), e2 = EXP2F(x2), e3 = EXP2F(x3);
            float e4 = EXP2F(x4), e5 = EXP2F(x5), e6 = EXP2F(x6), e7 = EXP2F(x7);
            float es = ((e0 + e1) + (e2 + e3)) + ((e4 + e5) + (e6 + e7));
            float ss = fmaf(e0, x0, fmaf(e1, x1, fmaf(e2, x2, e3 * x3)))
                     + fmaf(e4, x4, fmaf(e5, x5, fmaf(e6, x6, e7 * x7)));
            float simY = __fdividef(ss, es);          // = C2EXP * sim_c
            dn += EXP2F(simY);
            if (cA == rowk)
                sh_simpos[rh * 16 + n] = simY;        // unique writer per row
        }
        cA += 16;
    }

    // ---- fold denominators over the 4 q-groups (distinct concepts) ----
    {
        float t = dn;
        t += swz16(t);
        t += __shfl_xor(t, 32);
        if (lane < 16)
            atomicAdd(&sh_denom[rh * 16 + n], t);     // 4 colq waves per row
    }
    __syncthreads();

    // ---- in-block loss over 32 rows ----
    // lp = log(denom) - LT*(sim_pos + margin) = log(denom) - ln2*simY - 1.0
    float s = 0.f, cc = 0.f;
    if (tid < 32) {
        float lp = logf(sh_denom[tid] + 1e-8f) - LN2 * sh_simpos[tid] - 1.0f;
        float mk = (lab == 1) ? 1.0f : 0.0f;
        s = lp * mk;
        cc = mk;
    }
#pragma unroll
    for (int off = 16; off >= 1; off >>= 1) s  += __shfl_down(s, off);
#pragma unroll
    for (int off = 16; off >= 1; off >>= 1) cc += __shfl_down(cc, off);

    // ---- uncontended per-block partials + counter; last block finalizes ----
    if (tid == 0) {
        __hip_atomic_store(&part[2 * blockIdx.x],     s,  __ATOMIC_RELAXED, __HIP_MEMORY_SCOPE_AGENT);
        __hip_atomic_store(&part[2 * blockIdx.x + 1], cc, __ATOMIC_RELAXED, __HIP_MEMORY_SCOPE_AGENT);
        __threadfence();
        int g = __hip_atomic_fetch_add(gcnt, 1, __ATOMIC_ACQ_REL, __HIP_MEMORY_SCOPE_AGENT);
        sh_last = (g == NBLK - 1);
    }
    __syncthreads();
    if (sh_last) {
        float ts = 0.f, tc = 0.f;
        for (int i = tid; i < NBLK; i += 512) {
            ts += __hip_atomic_load(&part[2 * i],     __ATOMIC_RELAXED, __HIP_MEMORY_SCOPE_AGENT);
            tc += __hip_atomic_load(&part[2 * i + 1], __ATOMIC_RELAXED, __HIP_MEMORY_SCOPE_AGENT);
        }
#pragma unroll
        for (int off = 32; off >= 1; off >>= 1) {
            ts += __shfl_down(ts, off);
            tc += __shfl_down(tc, off);
        }
        if (lane == 0) { sh_fin[w] = ts; sh_fin[8 + w] = tc; }
        __syncthreads();
        if (tid == 0) {
            ts = 0.f; tc = 0.f;
#pragma unroll
            for (int i = 0; i < 8; ++i) { ts += sh_fin[i]; tc += sh_fin[8 + i]; }
            out[0] = (tc > 0.0f) ? (ts / tc) : ts;
        }
    }
}

extern "C" void kernel_launch(void* const* d_in, const int* in_sizes, int n_in,
                              void* d_out, int out_size, void* d_ws, size_t ws_size,
                              hipStream_t stream)
{
    const float* V      = (const float*)d_in[0];
    const int*   labels = (const int*)d_in[1];
    const float* P      = (const float*)d_in[2];
    float* out = (float*)d_out;
    int*   ws  = (int*)d_ws;
    _Float16* Pw = (_Float16*)((char*)d_ws + 16384);   // 8 x 512 KB packed P

    mpcl_prep<<<1024, 256, 0, stream>>>(P, Pw, ws);    // also zeroes gcnt
    mpcl_main<<<NBLK, 512, 0, stream>>>(V, labels, Pw, ws, out);
}

// Round 6
// 99.116 us; speedup vs baseline: 1.3137x; 1.3137x over previous
//
#include <hip/hip_runtime.h>

// B=128, K=256, M=8, D=128 ; rows = B*K = 32768 flattened (b,k)
#define LT      20.0f
#define LN2     0.69314718055994531f
#define C2EXP   28.853900817779268f   // LT/ln2 : e^(LT*x) = 2^(C2EXP*x)
#define CHUNKS  16                    // 16 chunks x 128 prototype-cols = 2048
#define NBLK    512                   // main grid: 512 blocks x 512 threads
#define PW_COPY 262144                // halves per Pw copy (512 KB / 2B)

typedef _Float16 half8 __attribute__((ext_vector_type(8)));
typedef float    f32x4 __attribute__((ext_vector_type(4)));

#if __has_builtin(__builtin_amdgcn_exp2f)
#define EXP2F(x) __builtin_amdgcn_exp2f(x)
#else
#define EXP2F(x) __expf(0.69314718055994531f * (x))
#endif

__device__ __forceinline__ float swz16(float x) {
    // xor lane^16 within 32-lane halves (BitMode: xor=16, and=0x1F)
    return __int_as_float(__builtin_amdgcn_ds_swizzle(__float_as_int(x), 0x401F));
}

// async global->LDS, 16B per lane; lds base must be wave-uniform
#define GLD16(gp, lp) __builtin_amdgcn_global_load_lds( \
    (const __attribute__((address_space(1))) void*)(gp), \
    (__attribute__((address_space(3))) void*)(lp), 16, 0, 0)

// ---- prep: f32 P -> f16 scaled by C2EXP, packed in fragment lane order,
// REPLICATED 8x so each XCD's L2 gets its own full copy (block g -> XCD g%8).
// Within a copy: half8 slot id = ch*2048 + colq*512 + cfrag*64 + lane
//   c = cfrag&3 (K-slice), h = cfrag>>2 (proto half), n = lane&15, q = lane>>4
//   col = colq*32 + (n>>2)*8 + (n&3) + 4*h ; gcol = ch*128+col ; d = c*32+q*8
__global__ __launch_bounds__(256)
void mpcl_prep(const float* __restrict__ P, _Float16* __restrict__ Pw)
{
    int copy = blockIdx.x & 7;
    int id   = (blockIdx.x >> 3) * 256 + threadIdx.x;     // 0..32767
    int ch    = id >> 11;
    int colq  = (id >> 9) & 3;
    int cfrag = (id >> 6) & 7;
    int lane  = id & 63;
    int n = lane & 15, q = lane >> 4;
    int c = cfrag & 3, h = cfrag >> 2;
    int col  = colq * 32 + ((n >> 2) << 3) + (n & 3) + (h << 2);
    int gcol = (ch << 7) + col;
    const float* src = P + ((size_t)gcol << 7) + c * 32 + q * 8;
    float4 a = *(const float4*)src;
    float4 b = *(const float4*)(src + 4);
    half8 hv;   // pre-scaled: MFMA emits y = C2EXP * sim directly
    hv[0] = (_Float16)(C2EXP * a.x); hv[1] = (_Float16)(C2EXP * a.y);
    hv[2] = (_Float16)(C2EXP * a.z); hv[3] = (_Float16)(C2EXP * a.w);
    hv[4] = (_Float16)(C2EXP * b.x); hv[5] = (_Float16)(C2EXP * b.y);
    hv[6] = (_Float16)(C2EXP * b.z); hv[7] = (_Float16)(C2EXP * b.w);
    *(half8*)(Pw + (size_t)copy * PW_COPY + (size_t)id * 8) = hv;
}

// Grid: 512 blocks x 512 thr (8 waves). Block owns 64 rows x all 2048 cols.
// wave w: rg=w>>2 (32-row group), colq=w&3 (4 concepts per 128-col chunk).
// Loop = round-3 structure (best measured): XCD-local Pw copy, dbuf LDS,
// counted s_waitcnt vmcnt(4) (no mid-loop drain), prescaled epilogue.
// TAIL REMOVED (round-5 diagnosis: ~40ns x nblk serialized cross-XCD
// atomics+fence = ~20us of the 51us): block ends with TWO PLAIN STORES of
// its partials; a 1-block finisher kernel reduces them. No atomics, no
// fences, no last-block logic anywhere.
__global__ __attribute__((amdgpu_flat_work_group_size(512, 512),
                          amdgpu_waves_per_eu(4, 4)))
void mpcl_main(const float* __restrict__ V,        // (32768, 128) f32
               const int*   __restrict__ labels,   // (32768)
               const _Float16* __restrict__ Pw,    // packed P, 8 copies
               float* __restrict__ part)           // (NBLK, 2) partials
{
    __shared__ __align__(16) _Float16 Pst[2][2048 * 8];   // 2 x 32 KB
    __shared__ float sh_denom[64];
    __shared__ float sh_simpos[64];

    const int tid  = threadIdx.x;
    const int lane = tid & 63;
    const int w    = tid >> 6;        // 0..7
    const int colq = w & 3;
    const int rg   = w >> 2;          // 0..1
    const int n    = lane & 15;
    const int q    = lane >> 4;
    const int rowbase = blockIdx.x * 64;

    if (tid < 64) { sh_denom[tid] = 0.0f; sh_simpos[tid] = 0.0f; }

    int lab = 0;
    if (tid < 64) lab = labels[rowbase + tid];    // prefetch early

    // XCD-local copy: main block b runs on XCD b%8 (round-robin dispatch),
    // reads the copy prep wrote from that same XCD.
    const _Float16* gbase = Pw + (size_t)(blockIdx.x & 7) * PW_COPY
                               + (size_t)(w * 256 + lane) * 8;

#define STAGE(CH, B) do {                                       \
    const _Float16* g_ = gbase + (size_t)(CH) * 16384;          \
    _Float16* l_ = &Pst[B][(w * 256) * 8];                      \
    GLD16(g_,        l_);                                       \
    GLD16(g_ +  512, l_ +  512);                                \
    GLD16(g_ + 1024, l_ + 1024);                                \
    GLD16(g_ + 1536, l_ + 1536);                                \
} while (0)

    // ---- V fragments (B operand), f16, register-resident (32 VGPR) ----
    half8 vh[2][4];
#pragma unroll
    for (int rf = 0; rf < 2; ++rf) {
        const float* vr = V + ((size_t)(rowbase + rg * 32 + rf * 16 + n) << 7) + q * 8;
#pragma unroll
        for (int c = 0; c < 4; ++c) {
            float4 x0 = *(const float4*)(vr + c * 32);
            float4 x1 = *(const float4*)(vr + c * 32 + 4);
            vh[rf][c][0] = (_Float16)x0.x; vh[rf][c][1] = (_Float16)x0.y;
            vh[rf][c][2] = (_Float16)x0.z; vh[rf][c][3] = (_Float16)x0.w;
            vh[rf][c][4] = (_Float16)x1.x; vh[rf][c][5] = (_Float16)x1.y;
            vh[rf][c][6] = (_Float16)x1.z; vh[rf][c][7] = (_Float16)x1.w;
        }
    }

    __syncthreads();   // sh_* init visible; (also drains vh loads, once)

    STAGE(0, 0);       // chunk 0 + 1 in flight (8 outstanding per wave)
    STAGE(1, 1);

    const int rowk0 = (rowbase + rg * 32 + n) & 255;        // positive concept, rf=0
    const int rowk1 = (rowbase + rg * 32 + 16 + n) & 255;   // rf=1
    const int aoff  = (colq * 512 + lane) * 8;              // half index of a1(c=0)

    float dn0 = 0.f, dn1 = 0.f;
    int cA = colq * 4 + q;

#pragma unroll 1
    for (int ch = 0; ch < CHUNKS; ++ch) {
        // wait for THIS chunk's 4 loads (the next chunk's 4 may stay in flight)
        if (ch < CHUNKS - 1) asm volatile("s_waitcnt vmcnt(4)" ::: "memory");
        else                 asm volatile("s_waitcnt vmcnt(0)" ::: "memory");
        __builtin_amdgcn_s_barrier();   // all waves' chunk-ch DMA visible

        const _Float16* base = &Pst[ch & 1][0];

        f32x4 acc1[2] = {{0.f,0.f,0.f,0.f},{0.f,0.f,0.f,0.f}};
        f32x4 acc2[2] = {{0.f,0.f,0.f,0.f},{0.f,0.f,0.f,0.f}};
#pragma unroll
        for (int c = 0; c < 4; ++c) {
            half8 a1 = *(const half8*)&base[aoff + c * 512];          // frag c
            half8 a2 = *(const half8*)&base[aoff + c * 512 + 2048];   // frag 4+c
            acc1[0] = __builtin_amdgcn_mfma_f32_16x16x32_f16(a1, vh[0][c], acc1[0], 0, 0, 0);
            acc1[1] = __builtin_amdgcn_mfma_f32_16x16x32_f16(a1, vh[1][c], acc1[1], 0, 0, 0);
            acc2[0] = __builtin_amdgcn_mfma_f32_16x16x32_f16(a2, vh[0][c], acc2[0], 0, 0, 0);
            acc2[1] = __builtin_amdgcn_mfma_f32_16x16x32_f16(a2, vh[1][c], acc2[1], 0, 0, 0);
        }

        // ---- epilogue: y = C2EXP*sim from MFMA; softmax-over-8 in-lane ----
#pragma unroll
        for (int rf = 0; rf < 2; ++rf) {
            float x0 = acc1[rf][0], x1 = acc1[rf][1], x2 = acc1[rf][2], x3 = acc1[rf][3];
            float x4 = acc2[rf][0], x5 = acc2[rf][1], x6 = acc2[rf][2], x7 = acc2[rf][3];
            float e0 = EXP2F(x0), e1 = EXP2F(x1), e2 = EXP2F(x2), e3 = EXP2F(x3);
            float e4 = EXP2F(x4), e5 = EXP2F(x5), e6 = EXP2F(x6), e7 = EXP2F(x7);
            float es = ((e0 + e1) + (e2 + e3)) + ((e4 + e5) + (e6 + e7));
            float ss = fmaf(e0, x0, fmaf(e1, x1, fmaf(e2, x2, e3 * x3)))
                     + fmaf(e4, x4, fmaf(e5, x5, fmaf(e6, x6, e7 * x7)));
            float simY = __fdividef(ss, es);          // = C2EXP * sim_c
            if (rf) dn1 += EXP2F(simY); else dn0 += EXP2F(simY);
            if (cA == (rf ? rowk1 : rowk0))
                sh_simpos[rg * 32 + rf * 16 + n] = simY;   // unique writer per row
        }
        cA += 16;

        __builtin_amdgcn_s_barrier();   // all waves done reading Pst[ch&1]
        if (ch + 2 < CHUNKS) STAGE(ch + 2, ch & 1);   // refill freed buffer
    }

    // ---- fold denominators over the 4 q-groups (distinct concepts) ----
#pragma unroll
    for (int rf = 0; rf < 2; ++rf) {
        float t = rf ? dn1 : dn0;
        t += swz16(t);
        t += __shfl_xor(t, 32);
        if (lane < 16)
            atomicAdd(&sh_denom[rg * 32 + rf * 16 + n], t);   // LDS atomic (cheap)
    }
    __syncthreads();

    // ---- in-block loss over 64 rows ----
    // lp = log(denom) - LT*(sim_pos + margin) = log(denom) - ln2*simY - 1.0
    float s = 0.f, cc = 0.f;
    if (tid < 64) {
        float lp = logf(sh_denom[tid] + 1e-8f) - LN2 * sh_simpos[tid] - 1.0f;
        float mk = (lab == 1) ? 1.0f : 0.0f;
        s = lp * mk;
        cc = mk;
    }
#pragma unroll
    for (int off = 32; off >= 1; off >>= 1) {
        s  += __shfl_down(s, off);
        cc += __shfl_down(cc, off);
    }

    // ---- plain per-block partial stores; finisher kernel reduces them ----
    if (tid == 0) {
        part[2 * blockIdx.x]     = s;
        part[2 * blockIdx.x + 1] = cc;
    }
}

// 1 block x 512 threads: reduce the 512 (s, cc) partial pairs.
// Visibility of mpcl_main's stores is guaranteed by stream ordering.
__global__ __launch_bounds__(512)
void mpcl_finish(const float* __restrict__ part, float* __restrict__ out)
{
    __shared__ float sh[16];
    const int tid  = threadIdx.x;
    const int lane = tid & 63;
    const int w    = tid >> 6;

    float s  = part[2 * tid];
    float cc = part[2 * tid + 1];
#pragma unroll
    for (int off = 32; off >= 1; off >>= 1) {
        s  += __shfl_down(s, off);
        cc += __shfl_down(cc, off);
    }
    if (lane == 0) { sh[w] = s; sh[8 + w] = cc; }
    __syncthreads();
    if (tid == 0) {
        float ts = 0.f, tc = 0.f;
#pragma unroll
        for (int i = 0; i < 8; ++i) { ts += sh[i]; tc += sh[8 + i]; }
        out[0] = (tc > 0.0f) ? (ts / tc) : ts;
    }
}

extern "C" void kernel_launch(void* const* d_in, const int* in_sizes, int n_in,
                              void* d_out, int out_size, void* d_ws, size_t ws_size,
                              hipStream_t stream)
{
    const float* V      = (const float*)d_in[0];
    const int*   labels = (const int*)d_in[1];
    const float* P      = (const float*)d_in[2];
    float* out  = (float*)d_out;
    float* part = (float*)d_ws;                        // (512, 2) partials
    _Float16* Pw = (_Float16*)((char*)d_ws + 16384);   // 8 x 512 KB packed P

    mpcl_prep<<<1024, 256, 0, stream>>>(P, Pw);
    mpcl_main<<<NBLK, 512, 0, stream>>>(V, labels, Pw, part);
    mpcl_finish<<<1, 512, 0, stream>>>(part, out);
}

// Round 7
// 97.206 us; speedup vs baseline: 1.3395x; 1.0196x over previous
//
#include <hip/hip_runtime.h>

// B=128, K=256, M=8, D=128 ; rows = B*K = 32768 flattened (b,k)
#define LT      20.0f
#define LN2     0.69314718055994531f
#define C2EXP   28.853900817779268f   // LT/ln2 : e^(LT*x) = 2^(C2EXP*x)
#define CHUNKS  16                    // 16 chunks x 128 prototype-cols = 2048
#define NBLK    512                   // main grid: 512 blocks x 1024 threads

typedef _Float16 half8 __attribute__((ext_vector_type(8)));
typedef float    f32x4 __attribute__((ext_vector_type(4)));

#if __has_builtin(__builtin_amdgcn_exp2f)
#define EXP2F(x) __builtin_amdgcn_exp2f(x)
#else
#define EXP2F(x) __expf(0.69314718055994531f * (x))
#endif

__device__ __forceinline__ float swz16(float x) {
    // xor lane^16 within 32-lane halves (BitMode: xor=16, and=0x1F)
    return __int_as_float(__builtin_amdgcn_ds_swizzle(__float_as_int(x), 0x401F));
}

// async global->LDS, 16B per lane; lds base must be wave-uniform
#define GLD16(gp, lp) __builtin_amdgcn_global_load_lds( \
    (const __attribute__((address_space(1))) void*)(gp), \
    (__attribute__((address_space(3))) void*)(lp), 16, 0, 0)

// ---- prep: f32 P -> f16 scaled by C2EXP, packed in fragment lane order.
// COALESCED READS: thread t handles (gcol = t>>4, dblk = t&15) -> 16
// consecutive threads read one contiguous 512B P row (vs r6's 512B-stride
// scatter). Writes are scattered 16B into the 512KB L2-resident Pw (cheap).
// Single copy (8x XCD replication was A/B-null in r2 vs r3).
// Inverse of the consumption layout:
//   slot = ch*2048 + colq*512 + cfrag*64 + lane, half8 per slot, where
//   lane=(q<<4)|n, cfrag=(h<<2)|c, col=colq*32+(n>>2)*8+(n&3)+4h, d=c*32+q*8
__global__ __launch_bounds__(256)
void mpcl_prep(const float* __restrict__ P, _Float16* __restrict__ Pw)
{
    int t    = blockIdx.x * 256 + threadIdx.x;   // 0..32767
    int gcol = t >> 4;                           // 0..2047 (concept*8+proto)
    int dblk = t & 15;                           // d/8
    const float* src = P + ((size_t)gcol << 7) + dblk * 8;
    float4 a = *(const float4*)src;
    float4 b = *(const float4*)(src + 4);

    int ch   = gcol >> 7, col  = gcol & 127;
    int colq = col >> 5,  col5 = col & 31;
    int g = col5 >> 3, p = col5 & 7;             // proto-group, proto
    int n = (g << 2) | (p & 3), h = p >> 2;
    int c = dblk >> 2, q = dblk & 3;
    int lane  = (q << 4) | n;
    int cfrag = (h << 2) | c;
    int slot  = ch * 2048 + colq * 512 + cfrag * 64 + lane;

    half8 hv;   // pre-scaled: MFMA emits y = C2EXP * sim directly
    hv[0] = (_Float16)(C2EXP * a.x); hv[1] = (_Float16)(C2EXP * a.y);
    hv[2] = (_Float16)(C2EXP * a.z); hv[3] = (_Float16)(C2EXP * a.w);
    hv[4] = (_Float16)(C2EXP * b.x); hv[5] = (_Float16)(C2EXP * b.y);
    hv[6] = (_Float16)(C2EXP * b.z); hv[7] = (_Float16)(C2EXP * b.w);
    *(half8*)(Pw + (size_t)slot * 8) = hv;
}

// Grid: 512 blocks x 1024 thr (16 waves) = 2 blocks/CU = 32 waves/CU =
// 8 waves/SIMD (r7 occupancy design: clock ~780MHz => issue-floor ~17us;
// r0-r6's 4 waves/SIMD left ~50% dependency-stall; 8 contexts cover it).
// Block owns 64 rows x all 2048 cols. wave w: colq=w&3, rg=w>>2 (16 rows).
// Per wave per chunk: 8 MFMA + ONE softmax epilogue (half of r6's work).
// Loop keeps r3/r6's proven pipeline: dbuf LDS, counted s_waitcnt vmcnt(2)
// (never 0 mid-loop), stage issued BEFORE the epilogue so DMA hides under
// it. launch_bounds(1024,8) pins VGPR<=64 (live set ~55; WRITE_SIZE is the
// spill tripwire). Ends with plain partial stores (tail removed in r6).
__global__ __launch_bounds__(1024, 8)
void mpcl_main(const float* __restrict__ V,        // (32768, 128) f32
               const int*   __restrict__ labels,   // (32768)
               const _Float16* __restrict__ Pw,    // packed P (prep)
               float* __restrict__ part)           // (NBLK, 2) partials
{
    __shared__ __align__(16) _Float16 Pst[2][2048 * 8];   // 2 x 32 KB
    __shared__ float sh_denom[64];
    __shared__ float sh_simpos[64];

    const int tid  = threadIdx.x;
    const int lane = tid & 63;
    const int w    = tid >> 6;        // 0..15
    const int colq = w & 3;
    const int rg   = w >> 2;          // 0..3 -> 16-row group
    const int n    = lane & 15;
    const int q    = lane >> 4;
    const int rowbase = blockIdx.x * 64;

    if (tid < 64) { sh_denom[tid] = 0.0f; sh_simpos[tid] = 0.0f; }

    int lab = 0;
    if (tid < 64) lab = labels[rowbase + tid];    // wave 0 only uses it

    // wave w stages half8 slots [w*128, +128) of each chunk: 2 GLD16
    const _Float16* gbase = Pw + (size_t)(w * 128 + lane) * 8;

#define STAGE(CH, B) do {                                       \
    const _Float16* g_ = gbase + (size_t)(CH) * 16384;          \
    _Float16* l_ = &Pst[B][(w * 128) * 8];                      \
    GLD16(g_,       l_);                                        \
    GLD16(g_ + 512, l_ + 512);                                  \
} while (0)

    // ---- V fragment (B operand): 16 rows, f16, register-resident (16 VGPR)
    half8 vh[4];
    {
        const float* vr = V + ((size_t)(rowbase + rg * 16 + n) << 7) + q * 8;
#pragma unroll
        for (int c = 0; c < 4; ++c) {
            float4 x0 = *(const float4*)(vr + c * 32);
            float4 x1 = *(const float4*)(vr + c * 32 + 4);
            vh[c][0] = (_Float16)x0.x; vh[c][1] = (_Float16)x0.y;
            vh[c][2] = (_Float16)x0.z; vh[c][3] = (_Float16)x0.w;
            vh[c][4] = (_Float16)x1.x; vh[c][5] = (_Float16)x1.y;
            vh[c][6] = (_Float16)x1.z; vh[c][7] = (_Float16)x1.w;
        }
    }
    __syncthreads();   // sh_* init visible before any epilogue writes

    STAGE(0, 0);       // chunks 0+1 in flight (4 outstanding per wave)
    STAGE(1, 1);

    const int rowk = (rowbase + rg * 16 + n) & 255;   // this row's own concept
    const int aoff = (colq * 512 + lane) * 8;         // half index of a1(c=0)

    float dn = 0.f;
    int cA = colq * 4 + q;

#pragma unroll 1
    for (int ch = 0; ch < CHUNKS; ++ch) {
        // at top of iter ch the last 2 issued loads are chunk ch+1's:
        // vmcnt(2) => chunk ch's DMA complete, ch+1's may stay in flight
        if (ch < CHUNKS - 1) asm volatile("s_waitcnt vmcnt(2)" ::: "memory");
        else                 asm volatile("s_waitcnt vmcnt(0)" ::: "memory");
        __builtin_amdgcn_s_barrier();   // all waves' chunk-ch DMA visible

        const _Float16* base = &Pst[ch & 1][0];

        f32x4 acc1 = {0.f, 0.f, 0.f, 0.f};
        f32x4 acc2 = {0.f, 0.f, 0.f, 0.f};
#pragma unroll
        for (int c = 0; c < 4; ++c) {
            half8 a1 = *(const half8*)&base[aoff + c * 512];          // frag c
            half8 a2 = *(const half8*)&base[aoff + c * 512 + 2048];   // frag 4+c
            acc1 = __builtin_amdgcn_mfma_f32_16x16x32_f16(a1, vh[c], acc1, 0, 0, 0);
            acc2 = __builtin_amdgcn_mfma_f32_16x16x32_f16(a2, vh[c], acc2, 0, 0, 0);
        }

        asm volatile("s_waitcnt lgkmcnt(0)" ::: "memory");  // ds_reads retired
        __builtin_amdgcn_s_barrier();   // all waves done reading Pst[ch&1]
        if (ch + 2 < CHUNKS) STAGE(ch + 2, ch & 1);   // DMA hides under epilogue

        // ---- epilogue: y = C2EXP*sim from MFMA; softmax-over-8 in-lane ----
        {
            float x0 = acc1[0], x1 = acc1[1], x2 = acc1[2], x3 = acc1[3];
            float x4 = acc2[0], x5 = acc2[1], x6 = acc2[2], x7 = acc2[3];
            float e0 = EXP2F(x0), e1 = EXP2F(x1), e2 = EXP2F(x2), e3 = EXP2F(x3);
            float e4 = EXP2F(x4), e5 = EXP2F(x5), e6 = EXP2F(x6), e7 = EXP2F(x7);
            float es = ((e0 + e1) + (e2 + e3)) + ((e4 + e5) + (e6 + e7));
            float ss = fmaf(e0, x0, fmaf(e1, x1, fmaf(e2, x2, e3 * x3)))
                     + fmaf(e4, x4, fmaf(e5, x5, fmaf(e6, x6, e7 * x7)));
            float simY = __fdividef(ss, es);          // = C2EXP * sim_c
            dn += EXP2F(simY);
            if (cA == rowk)
                sh_simpos[rg * 16 + n] = simY;        // unique writer per row
        }
        cA += 16;
    }

    // ---- fold denominators over the 4 q-groups (distinct concepts) ----
    {
        float t = dn;
        t += swz16(t);                 // q 0<->1, 2<->3
        t += __shfl_xor(t, 32);        // q 0<->2
        if (lane < 16)
            atomicAdd(&sh_denom[rg * 16 + n], t);   // 4 colq waves per row
    }
    __syncthreads();

    // ---- in-block loss over 64 rows (wave 0 holds rows 0..63) ----
    // lp = log(denom) - LT*(sim_pos + margin) = log(denom) - ln2*simY - 1.0
    if (w == 0) {
        float lp = logf(sh_denom[lane] + 1e-8f) - LN2 * sh_simpos[lane] - 1.0f;
        float mk = (lab == 1) ? 1.0f : 0.0f;
        float s  = lp * mk;
        float cc = mk;
#pragma unroll
        for (int off = 32; off >= 1; off >>= 1) {
            s  += __shfl_down(s, off);
            cc += __shfl_down(cc, off);
        }
        if (lane == 0) {               // plain stores; finisher reduces
            part[2 * blockIdx.x]     = s;
            part[2 * blockIdx.x + 1] = cc;
        }
    }
}

// 1 block x 512 threads: reduce the 512 (s, cc) partial pairs.
// Visibility of mpcl_main's stores is guaranteed by stream ordering.
__global__ __launch_bounds__(512)
void mpcl_finish(const float* __restrict__ part, float* __restrict__ out)
{
    __shared__ float sh[16];
    const int tid  = threadIdx.x;
    const int lane = tid & 63;
    const int w    = tid >> 6;

    float s  = part[2 * tid];
    float cc = part[2 * tid + 1];
#pragma unroll
    for (int off = 32; off >= 1; off >>= 1) {
        s  += __shfl_down(s, off);
        cc += __shfl_down(cc, off);
    }
    if (lane == 0) { sh[w] = s; sh[8 + w] = cc; }
    __syncthreads();
    if (tid == 0) {
        float ts = 0.f, tc = 0.f;
#pragma unroll
        for (int i = 0; i < 8; ++i) { ts += sh[i]; tc += sh[8 + i]; }
        out[0] = (tc > 0.0f) ? (ts / tc) : ts;
    }
}

extern "C" void kernel_launch(void* const* d_in, const int* in_sizes, int n_in,
                              void* d_out, int out_size, void* d_ws, size_t ws_size,
                              hipStream_t stream)
{
    const float* V      = (const float*)d_in[0];
    const int*   labels = (const int*)d_in[1];
    const float* P      = (const float*)d_in[2];
    float* out  = (float*)d_out;
    float* part = (float*)d_ws;                        // (512, 2) partials
    _Float16* Pw = (_Float16*)((char*)d_ws + 16384);   // 512 KB packed P

    mpcl_prep<<<128, 256, 0, stream>>>(P, Pw);
    mpcl_main<<<NBLK, 1024, 0, stream>>>(V, labels, Pw, part);
    mpcl_finish<<<1, 512, 0, stream>>>(part, out);
}

// Round 8
// 93.679 us; speedup vs baseline: 1.3900x; 1.0377x over previous
//
#include <hip/hip_runtime.h>

// B=128, K=256, M=8, D=128 ; rows = B*K = 32768 flattened (b,k)
// KEY: reference masks loss by (label==1) -> ~half the rows are DEAD WORK.
// We compact positive rows (mpcl_compact) and process only those.
#define LT      20.0f
#define LN2     0.69314718055994531f
#define C2EXP   28.853900817779268f   // LT/ln2 : e^(LT*x) = 2^(C2EXP*x)
#define CHUNKS  16                    // 16 chunks x 128 prototype-cols = 2048
#define NBLK    1024                  // main grid (32 rows/block, worst case)

typedef _Float16 half8 __attribute__((ext_vector_type(8)));
typedef float    f32x4 __attribute__((ext_vector_type(4)));

#if __has_builtin(__builtin_amdgcn_exp2f)
#define EXP2F(x) __builtin_amdgcn_exp2f(x)
#else
#define EXP2F(x) __expf(0.69314718055994531f * (x))
#endif

__device__ __forceinline__ float swz16(float x) {
    // xor lane^16 within 32-lane halves (BitMode: xor=16, and=0x1F)
    return __int_as_float(__builtin_amdgcn_ds_swizzle(__float_as_int(x), 0x401F));
}

// async global->LDS, 16B per lane; lds base must be wave-uniform
#define GLD16(gp, lp) __builtin_amdgcn_global_load_lds( \
    (const __attribute__((address_space(1))) void*)(gp), \
    (__attribute__((address_space(3))) void*)(lp), 16, 0, 0)

// ---- prep: f32 P -> f16 scaled by C2EXP, packed in fragment lane order.
// Coalesced reads (16 threads per contiguous 512B P row), scattered 16B
// writes into L2-resident Pw. Inverse of the consumption layout:
//   slot = ch*2048 + colq*512 + cfrag*64 + lane, half8 per slot, where
//   lane=(q<<4)|n, cfrag=(h<<2)|c, col=colq*32+(n>>2)*8+(n&3)+4h, d=c*32+q*8
__global__ __launch_bounds__(256)
void mpcl_prep(const float* __restrict__ P, _Float16* __restrict__ Pw)
{
    int t    = blockIdx.x * 256 + threadIdx.x;   // 0..32767
    int gcol = t >> 4;                           // 0..2047 (concept*8+proto)
    int dblk = t & 15;                           // d/8
    const float* src = P + ((size_t)gcol << 7) + dblk * 8;
    float4 a = *(const float4*)src;
    float4 b = *(const float4*)(src + 4);

    int ch   = gcol >> 7, col  = gcol & 127;
    int colq = col >> 5,  col5 = col & 31;
    int g = col5 >> 3, p = col5 & 7;             // proto-group, proto
    int n = (g << 2) | (p & 3), h = p >> 2;
    int c = dblk >> 2, q = dblk & 3;
    int lane  = (q << 4) | n;
    int cfrag = (h << 2) | c;
    int slot  = ch * 2048 + colq * 512 + cfrag * 64 + lane;

    half8 hv;   // pre-scaled: MFMA emits y = C2EXP * sim directly
    hv[0] = (_Float16)(C2EXP * a.x); hv[1] = (_Float16)(C2EXP * a.y);
    hv[2] = (_Float16)(C2EXP * a.z); hv[3] = (_Float16)(C2EXP * a.w);
    hv[4] = (_Float16)(C2EXP * b.x); hv[5] = (_Float16)(C2EXP * b.y);
    hv[6] = (_Float16)(C2EXP * b.z); hv[7] = (_Float16)(C2EXP * b.w);
    *(half8*)(Pw + (size_t)slot * 8) = hv;
}

// ---- compact: build ordered list of rows with label==1.
// Single block, 1024 threads. Labels prefetched to 32 regs (one latency),
// ballot -> per-64-row counts -> LDS scan -> ordered write. Tail padded
// with row 0 so main's gathers stay in-bounds (validity masked by npos).
__global__ __launch_bounds__(1024)
void mpcl_compact(const int* __restrict__ labels, int* __restrict__ ridx,
                  int* __restrict__ npos)
{
    __shared__ int wcnt[512];
    __shared__ int wsum[8];
    __shared__ int sbase[512];
    __shared__ int tot;
    const int tid = threadIdx.x, lane = tid & 63, w = tid >> 6;   // w 0..15

    int lab[32];
#pragma unroll
    for (int i = 0; i < 32; ++i) lab[i] = labels[i * 1024 + tid];
#pragma unroll
    for (int i = 0; i < 32; ++i) {
        unsigned long long m = __ballot(lab[i] == 1);
        if (lane == 0) wcnt[i * 16 + w] = __popcll(m);   // chunk ci=i*16+w
    }
    __syncthreads();

    int v = 0, orig = 0;
    if (tid < 512) { v = wcnt[tid]; orig = v; }
#pragma unroll
    for (int off = 1; off < 64; off <<= 1) {             // intra-wave scan
        int t = __shfl_up(v, off);
        if (lane >= off) v += t;
    }
    if (lane == 63 && w < 8) wsum[w] = v;
    __syncthreads();
    if (tid == 0) {
        int acc = 0;
#pragma unroll
        for (int i = 0; i < 8; ++i) { int t = wsum[i]; wsum[i] = acc; acc += t; }
        tot = acc; npos[0] = acc;
    }
    __syncthreads();
    if (tid < 512) sbase[tid] = v - orig + wsum[w];      // exclusive base
    __syncthreads();

#pragma unroll
    for (int i = 0; i < 32; ++i) {                       // ordered scatter
        unsigned long long m = __ballot(lab[i] == 1);
        int pos = sbase[i * 16 + w] + __popcll(m & ((1ull << lane) - 1));
        if (lab[i] == 1) ridx[pos] = i * 1024 + tid;
    }
    for (int j = tot + tid; j < 32768; j += 1024) ridx[j] = 0;   // pad
}

// Grid: 1024 blocks x 512 thr (8 waves); block owns 32 COMPACTED rows x all
// 2048 cols. Blocks beyond ceil(npos/32) exit instantly (~512 at npos~16k:
// active blocks ~512 = 2/CU). wave w: colq=w&3, rg=w>>2 (16 rows).
// Loop = proven r6/r7 pipeline: dbuf LDS, counted vmcnt(4) (never 0
// mid-loop), stage issued before the epilogue so DMA hides under it.
// HALF the MFMA/exp/div of round 7 via row compaction (exact: rows indep).
__global__ __attribute__((amdgpu_flat_work_group_size(512, 512),
                          amdgpu_waves_per_eu(4, 4)))
void mpcl_main(const float* __restrict__ V,        // (32768, 128) f32
               const _Float16* __restrict__ Pw,    // packed P (prep)
               const int* __restrict__ ridx,       // compacted rows
               const int* __restrict__ npos,
               float* __restrict__ part)           // (NBLK, 2) partials
{
    __shared__ __align__(16) _Float16 Pst[2][2048 * 8];   // 2 x 32 KB
    __shared__ float sh_denom[32];
    __shared__ float sh_simpos[32];

    const int np = *npos;
    const int rowbase = blockIdx.x * 32;
    if (rowbase >= np) return;                    // uniform early exit

    const int tid  = threadIdx.x;
    const int lane = tid & 63;
    const int w    = tid >> 6;        // 0..7
    const int colq = w & 3;
    const int rg   = w >> 2;          // 0..1 -> 16-row group
    const int n    = lane & 15;
    const int q    = lane >> 4;

    if (tid < 32) { sh_denom[tid] = 0.0f; sh_simpos[tid] = 0.0f; }

    // wave w stages half8 slots [w*256, +256) of each chunk: 4 GLD16
    const _Float16* gbase = Pw + (size_t)(w * 256 + lane) * 8;

#define STAGE(CH, B) do {                                       \
    const _Float16* g_ = gbase + (size_t)(CH) * 16384;          \
    _Float16* l_ = &Pst[B][(w * 256) * 8];                      \
    GLD16(g_,        l_);                                       \
    GLD16(g_ +  512, l_ +  512);                                \
    GLD16(g_ + 1024, l_ + 1024);                                \
    GLD16(g_ + 1536, l_ + 1536);                                \
} while (0)

    // ---- V fragment (B operand): 16 gathered rows, f16, reg-resident ----
    const int myrow = ridx[rowbase + rg * 16 + n];   // per-lane row gather
    half8 vh[4];
    {
        const float* vr = V + ((size_t)myrow << 7) + q * 8;
#pragma unroll
        for (int c = 0; c < 4; ++c) {
            float4 x0 = *(const float4*)(vr + c * 32);
            float4 x1 = *(const float4*)(vr + c * 32 + 4);
            vh[c][0] = (_Float16)x0.x; vh[c][1] = (_Float16)x0.y;
            vh[c][2] = (_Float16)x0.z; vh[c][3] = (_Float16)x0.w;
            vh[c][4] = (_Float16)x1.x; vh[c][5] = (_Float16)x1.y;
            vh[c][6] = (_Float16)x1.z; vh[c][7] = (_Float16)x1.w;
        }
    }
    __syncthreads();   // sh_* init visible before any epilogue writes

    STAGE(0, 0);       // chunks 0+1 in flight (8 outstanding per wave)
    STAGE(1, 1);

    const int rowk = myrow & 255;                 // this row's own concept
    const int aoff = (colq * 512 + lane) * 8;     // half index of a1(c=0)

    float dn = 0.f;
    int cA = colq * 4 + q;

#pragma unroll 1
    for (int ch = 0; ch < CHUNKS; ++ch) {
        // outstanding after prologue/steady state: this chunk's 4 + next's 4
        if (ch < CHUNKS - 1) asm volatile("s_waitcnt vmcnt(4)" ::: "memory");
        else                 asm volatile("s_waitcnt vmcnt(0)" ::: "memory");
        __builtin_amdgcn_s_barrier();   // all waves' chunk-ch DMA visible

        const _Float16* base = &Pst[ch & 1][0];

        f32x4 acc1 = {0.f, 0.f, 0.f, 0.f};
        f32x4 acc2 = {0.f, 0.f, 0.f, 0.f};
#pragma unroll
        for (int c = 0; c < 4; ++c) {
            half8 a1 = *(const half8*)&base[aoff + c * 512];          // frag c
            half8 a2 = *(const half8*)&base[aoff + c * 512 + 2048];   // frag 4+c
            acc1 = __builtin_amdgcn_mfma_f32_16x16x32_f16(a1, vh[c], acc1, 0, 0, 0);
            acc2 = __builtin_amdgcn_mfma_f32_16x16x32_f16(a2, vh[c], acc2, 0, 0, 0);
        }

        asm volatile("s_waitcnt lgkmcnt(0)" ::: "memory");  // ds_reads retired
        __builtin_amdgcn_s_barrier();   // all waves done reading Pst[ch&1]
        if (ch + 2 < CHUNKS) STAGE(ch + 2, ch & 1);   // DMA hides under epilogue

        // ---- epilogue: y = C2EXP*sim from MFMA; softmax-over-8 in-lane ----
        {
            float x0 = acc1[0], x1 = acc1[1], x2 = acc1[2], x3 = acc1[3];
            float x4 = acc2[0], x5 = acc2[1], x6 = acc2[2], x7 = acc2[3];
            float e0 = EXP2F(x0), e1 = EXP2F(x1), e2 = EXP2F(x2), e3 = EXP2F(x3);
            float e4 = EXP2F(x4), e5 = EXP2F(x5), e6 = EXP2F(x6), e7 = EXP2F(x7);
            float es = ((e0 + e1) + (e2 + e3)) + ((e4 + e5) + (e6 + e7));
            float ss = fmaf(e0, x0, fmaf(e1, x1, fmaf(e2, x2, e3 * x3)))
                     + fmaf(e4, x4, fmaf(e5, x5, fmaf(e6, x6, e7 * x7)));
            float simY = __fdividef(ss, es);          // = C2EXP * sim_c
            dn += EXP2F(simY);
            if (cA == rowk)
                sh_simpos[rg * 16 + n] = simY;        // unique writer per row
        }
        cA += 16;
    }

    // ---- fold denominators over the 4 q-groups (distinct concepts) ----
    {
        float t = dn;
        t += swz16(t);                 // q 0<->1, 2<->3
        t += __shfl_xor(t, 32);        // q 0<->2
        if (lane < 16)
            atomicAdd(&sh_denom[rg * 16 + n], t);   // 4 colq waves per row
    }
    __syncthreads();

    // ---- block loss over its <=32 compacted rows (all label==1) ----
    // lp = log(denom) - LT*(sim_pos + margin) = log(denom) - ln2*simY - 1.0
    if (w == 0) {
        float s = 0.f, cc = 0.f;
        if (lane < 32 && rowbase + lane < np) {
            s  = logf(sh_denom[lane] + 1e-8f) - LN2 * sh_simpos[lane] - 1.0f;
            cc = 1.0f;
        }
#pragma unroll
        for (int off = 32; off >= 1; off >>= 1) {
            s  += __shfl_down(s, off);
            cc += __shfl_down(cc, off);
        }
        if (lane == 0) {               // plain stores; finisher reduces
            part[2 * blockIdx.x]     = s;
            part[2 * blockIdx.x + 1] = cc;
        }
    }
}

// 1 block x 512 threads: reduce the active blocks' (s, cc) partials.
// Visibility of mpcl_main's stores is guaranteed by stream ordering.
__global__ __launch_bounds__(512)
void mpcl_finish(const float* __restrict__ part, const int* __restrict__ npos,
                 float* __restrict__ out)
{
    __shared__ float sh[16];
    const int tid  = threadIdx.x;
    const int lane = tid & 63;
    const int w    = tid >> 6;
    const int nact = (*npos + 31) >> 5;           // active main blocks

    float s = 0.f, cc = 0.f;
    for (int i = tid; i < nact; i += 512) {
        s  += part[2 * i];
        cc += part[2 * i + 1];
    }
#pragma unroll
    for (int off = 32; off >= 1; off >>= 1) {
        s  += __shfl_down(s, off);
        cc += __shfl_down(cc, off);
    }
    if (lane == 0) { sh[w] = s; sh[8 + w] = cc; }
    __syncthreads();
    if (tid == 0) {
        float ts = 0.f, tc = 0.f;
#pragma unroll
        for (int i = 0; i < 8; ++i) { ts += sh[i]; tc += sh[8 + i]; }
        out[0] = (tc > 0.0f) ? (ts / tc) : ts;
    }
}

extern "C" void kernel_launch(void* const* d_in, const int* in_sizes, int n_in,
                              void* d_out, int out_size, void* d_ws, size_t ws_size,
                              hipStream_t stream)
{
    const float* V      = (const float*)d_in[0];
    const int*   labels = (const int*)d_in[1];
    const float* P      = (const float*)d_in[2];
    float* out = (float*)d_out;

    int*      npos = (int*)d_ws;                        // [0]
    float*    part = (float*)((char*)d_ws + 256);       // 1024 x 2 floats
    int*      ridx = (int*)((char*)d_ws + 16384);       // 128 KB
    _Float16* Pw   = (_Float16*)((char*)d_ws + 262144); // 512 KB packed P

    mpcl_prep<<<128, 256, 0, stream>>>(P, Pw);
    mpcl_compact<<<1, 1024, 0, stream>>>(labels, ridx, npos);
    mpcl_main<<<NBLK, 512, 0, stream>>>(V, Pw, ridx, npos, part);
    mpcl_finish<<<1, 512, 0, stream>>>(part, npos, out);
}